// Round 6
// baseline (48.102 us; speedup 1.0000x reference)
//
#include <hip/hip_runtime.h>

typedef unsigned short ushort_t;
typedef __bf16 bf16x8 __attribute__((ext_vector_type(8)));
typedef float f32x4 __attribute__((ext_vector_type(4)));
typedef ushort_t ushort8 __attribute__((ext_vector_type(8)));

static __device__ __forceinline__ ushort_t f2bf(float f) {
    __bf16 b = (__bf16)f;   // RNE convert
    return __builtin_bit_cast(ushort_t, b);
}

#define GLOAD_LDS16(gptr, lptr)                                                        \
    __builtin_amdgcn_global_load_lds(                                                  \
        (const __attribute__((address_space(1))) void*)(gptr),                         \
        (__attribute__((address_space(3))) void*)(lptr), 16, 0, 0)

#define CFENCE() asm volatile("" ::: "memory")
#define LGKM0()  asm volatile("s_waitcnt lgkmcnt(0)" ::: "memory")

template <int N> __device__ __forceinline__ void waitcnt_vm() {
    if constexpr (N == 0)      asm volatile("s_waitcnt vmcnt(0)" ::: "memory");
    else if constexpr (N == 2) asm volatile("s_waitcnt vmcnt(2)" ::: "memory");
    else if constexpr (N == 4) asm volatile("s_waitcnt vmcnt(4)" ::: "memory");
    else if constexpr (N == 8) asm volatile("s_waitcnt vmcnt(8)" ::: "memory");
}

// ---------------------------------------------------------------------------
// gemm-a: V[M][N] = bf16( A32[M][K] @ B[N][K]^T + b_in[r(col)] )
// A32 is fp32 (x), reg-staged with in-register bf16 convert (3-buffer);
// B is bf16 via global_load_lds (3-buffer, counted vmcnt).
// 128x128 tile, 256 threads, 4 waves 2x2, BK=32. K=N=1024 fixed-ish.
__global__ __launch_bounds__(256)
void gemm_a(const float* __restrict__ A32, const ushort_t* __restrict__ B,
            const float* __restrict__ b_in, ushort_t* __restrict__ V) {
    constexpr int K = 1024, N = 1024, T = 32;
    constexpr int ABUF = 128 * 32, BBUF = 128 * 32;   // ushorts per buffer
    __shared__ alignas(16) ushort_t ls[3 * (ABUF + BBUF)];
    ushort_t* Ab = ls;
    ushort_t* Bb = ls + 3 * ABUF;

    const int b = blockIdx.x;
    const int swz = (b & 7) * 32 + (b >> 3);
    const int rA = (swz >> 3) * 128, rB = (swz & 7) * 128;

    const int tid  = threadIdx.x;
    const int lane = tid & 63;
    const int wv   = tid >> 6;
    const int wr   = wv >> 1, wc = wv & 1;
    const int fr   = lane & 15, fq = lane >> 4;

    const int ar = tid >> 2;           // staging row (also +64)
    const int ac = (tid & 3) * 8;      // staging col (k within tile)

    f32x4 acc[4][4] = {};
    float4 areg[4];

    auto aload = [&](int k0) {
        const float* p0 = A32 + (size_t)(rA + ar) * K + k0 + ac;
        const float* p1 = A32 + (size_t)(rA + ar + 64) * K + k0 + ac;
        areg[0] = ((const float4*)p0)[0]; areg[1] = ((const float4*)p0)[1];
        areg[2] = ((const float4*)p1)[0]; areg[3] = ((const float4*)p1)[1];
    };
    auto awrite = [&](int buf) {
        ushort8 lo, hi;
        lo[0]=f2bf(areg[0].x); lo[1]=f2bf(areg[0].y); lo[2]=f2bf(areg[0].z); lo[3]=f2bf(areg[0].w);
        lo[4]=f2bf(areg[1].x); lo[5]=f2bf(areg[1].y); lo[6]=f2bf(areg[1].z); lo[7]=f2bf(areg[1].w);
        hi[0]=f2bf(areg[2].x); hi[1]=f2bf(areg[2].y); hi[2]=f2bf(areg[2].z); hi[3]=f2bf(areg[2].w);
        hi[4]=f2bf(areg[3].x); hi[5]=f2bf(areg[3].y); hi[6]=f2bf(areg[3].z); hi[7]=f2bf(areg[3].w);
        *(ushort8*)&Ab[buf * ABUF + ar * 32 + ac]        = lo;
        *(ushort8*)&Ab[buf * ABUF + (ar + 64) * 32 + ac] = hi;
    };
    auto bstage = [&](int k0, int buf) {
        #pragma unroll
        for (int q = 0; q < 2; ++q) {
            int c = q * 256 + tid;
            GLOAD_LDS16(B + (size_t)(rB + (c >> 2)) * K + k0 + (c & 3) * 8,
                        &Bb[buf * BBUF + c * 8]);
        }
    };
    auto compute = [&](int buf) {
        bf16x8 af[4], bfv[4];
        #pragma unroll
        for (int i = 0; i < 4; ++i)
            af[i] = *(const bf16x8*)&Ab[buf * ABUF + (wr * 64 + i * 16 + fr) * 32 + fq * 8];
        #pragma unroll
        for (int j = 0; j < 4; ++j)
            bfv[j] = *(const bf16x8*)&Bb[buf * BBUF + (wc * 64 + j * 16 + fr) * 32 + fq * 8];
        #pragma unroll
        for (int i = 0; i < 4; ++i)
            #pragma unroll
            for (int j = 0; j < 4; ++j)
                acc[i][j] = __builtin_amdgcn_mfma_f32_16x16x32_bf16(af[i], bfv[j], acc[i][j], 0, 0, 0);
    };

    // prologue: tiles 0,1 staged; tile-0 A written; B1 left in flight
    bstage(0, 0);            // vm +2
    aload(0);                // vm +4
    bstage(32, 1);           // vm +2  (total 8)
    awrite(0);               // compiler waits areg(0) -> vmcnt(2); B0 also landed
    aload(32);               // areg = tile 1
    LGKM0();
    __builtin_amdgcn_s_barrier(); CFENCE();

    for (int t = 0; t < T - 2; ++t) {
        const int cur = t % 3, nx1 = (t + 1) % 3, nx2 = (t + 2) % 3;
        bstage((t + 2) << 5, nx2);   // prefetch B tile t+2 (buffer free: readers done)
        compute(cur);
        awrite(nx1);                  // compiler-inserted vmcnt covers areg(t+1) & B(t+1)
        aload((t + 2) << 5);          // areg = tile t+2
        LGKM0();                      // A ds_writes + frag ds_reads drained
        CFENCE(); __builtin_amdgcn_s_barrier(); CFENCE();
    }
    {   // t = T-2
        const int cur = (T - 2) % 3, nx1 = (T - 1) % 3;
        compute(cur);
        awrite(nx1);                  // waits remaining loads (B(T-1)+A(T-1))
        LGKM0();
        CFENCE(); __builtin_amdgcn_s_barrier(); CFENCE();
        compute(nx1);                 // t = T-1
    }

    // epilogue: v' = acc + b_in[r(col)], bf16 store
    const int orow0 = rA + wr * 64 + fq * 4;
    const int ocol0 = rB + wc * 64 + fr;
    #pragma unroll
    for (int i = 0; i < 4; ++i)
        #pragma unroll
        for (int j = 0; j < 4; ++j) {
            const int col = ocol0 + j * 16;
            const float bv = b_in[(col >> 6) * 192 + 128 + (col & 63)];
            #pragma unroll
            for (int r = 0; r < 4; ++r)
                V[(size_t)(orow0 + i * 16 + r) * N + col] = f2bf(acc[i][j][r] + bv);
        }
}

// ---------------------------------------------------------------------------
// gemm-b: out[M][N] = V[M][K] @ W[N][K]^T + bias[n], bf16 in, fp32 out.
// r5 triple-buffered counted-vmcnt core, 128x128, 4 waves 2x2.
__global__ __launch_bounds__(256)
void gemm_b(const ushort_t* __restrict__ A, const ushort_t* __restrict__ B,
            const float* __restrict__ bias, float* __restrict__ C) {
    constexpr int K = 1024, N = 1024, T = 32;
    constexpr int HALF = 256 * 32;
    __shared__ alignas(16) ushort_t ls[3 * HALF];

    const int b = blockIdx.x;
    const int swz = (b & 7) * 32 + (b >> 3);
    const int rA = (swz >> 3) * 128, rB = (swz & 7) * 128;

    const int tid  = threadIdx.x;
    const int lane = tid & 63;
    const int wv   = tid >> 6;
    const int wr   = wv >> 1, wc = wv & 1;
    const int fr   = lane & 15, fq = lane >> 4;

    f32x4 acc[4][4] = {};

    auto stage = [&](int k0, int buf) {
        #pragma unroll
        for (int q = 0; q < 2; ++q) {
            int c = q * 256 + tid;
            GLOAD_LDS16(A + (size_t)(rA + (c >> 2)) * K + k0 + (c & 3) * 8,
                        &ls[buf * HALF + c * 8]);
        }
        #pragma unroll
        for (int q = 0; q < 2; ++q) {
            int c = q * 256 + tid;
            GLOAD_LDS16(B + (size_t)(rB + (c >> 2)) * K + k0 + (c & 3) * 8,
                        &ls[buf * HALF + 4096 + c * 8]);
        }
    };
    auto compute = [&](int buf) {
        bf16x8 af[4], bfv[4];
        #pragma unroll
        for (int i = 0; i < 4; ++i)
            af[i] = *(const bf16x8*)&ls[buf * HALF + (wr * 64 + i * 16 + fr) * 32 + fq * 8];
        #pragma unroll
        for (int j = 0; j < 4; ++j)
            bfv[j] = *(const bf16x8*)&ls[buf * HALF + 4096 + (wc * 64 + j * 16 + fr) * 32 + fq * 8];
        #pragma unroll
        for (int i = 0; i < 4; ++i)
            #pragma unroll
            for (int j = 0; j < 4; ++j)
                acc[i][j] = __builtin_amdgcn_mfma_f32_16x16x32_bf16(af[i], bfv[j], acc[i][j], 0, 0, 0);
    };

    stage(0, 0);
    stage(32, 1);
    for (int t = 0; t < T - 2; ++t) {
        stage((t + 2) << 5, (t + 2) % 3);
        waitcnt_vm<8>();
        __builtin_amdgcn_s_barrier(); CFENCE();
        compute(t % 3);
        CFENCE(); __builtin_amdgcn_s_barrier(); CFENCE();
    }
    waitcnt_vm<4>();
    __builtin_amdgcn_s_barrier(); CFENCE();
    compute((T - 2) % 3);
    CFENCE();
    waitcnt_vm<0>();
    __builtin_amdgcn_s_barrier(); CFENCE();
    compute((T - 1) % 3);

    const int orow0 = rA + wr * 64 + fq * 4;
    const int ocol0 = rB + wc * 64 + fr;
    #pragma unroll
    for (int i = 0; i < 4; ++i)
        #pragma unroll
        for (int j = 0; j < 4; ++j) {
            const int col = ocol0 + j * 16;
            const float bv = bias[col];
            #pragma unroll
            for (int r = 0; r < 4; ++r)
                C[(size_t)(orow0 + i * 16 + r) * N + col] = acc[i][j][r] + bv;
        }
}

// ---------------------------------------------------------------------------
// prep: [0,128): w_out fp32->bf16; [128,384): Wvb[j][:] = bf16(w_in[r(j)][:]).
__global__ __launch_bounds__(256)
void prep(const float* __restrict__ w_in, const float* __restrict__ w_out,
          ushort_t* __restrict__ wob, ushort_t* __restrict__ Wvb) {
    const int b = blockIdx.x;
    const int t = threadIdx.x;
    if (b < 128) {
        #pragma unroll
        for (int p = 0; p < 8; ++p) {
            int i = b * 2048 + p * 256 + t;
            float4 v = ((const float4*)w_out)[i];
            ushort4 o; o.x = f2bf(v.x); o.y = f2bf(v.y); o.z = f2bf(v.z); o.w = f2bf(v.w);
            ((ushort4*)wob)[i] = o;
        }
    } else {
        const int j = (b - 128) * 4 + (t >> 6);          // v-channel row
        const int lane = t & 63;
        const int r = (j >> 6) * 192 + 128 + (j & 63);   // w_in row
        const float4* src = (const float4*)(w_in + (size_t)r * 1024);
        ushort4* dst = (ushort4*)(Wvb + (size_t)j * 1024);
        #pragma unroll
        for (int k = 0; k < 4; ++k) {
            int i = k * 64 + lane;
            float4 v = src[i];
            ushort4 o; o.x = f2bf(v.x); o.y = f2bf(v.y); o.z = f2bf(v.z); o.w = f2bf(v.w);
            dst[i] = o;
        }
    }
}

// ---------------------------------------------------------------------------
extern "C" void kernel_launch(void* const* d_in, const int* in_sizes, int n_in,
                              void* d_out, int out_size, void* d_ws, size_t ws_size,
                              hipStream_t stream) {
    const float* x     = (const float*)d_in[0];   // (2,2048,1024)
    const float* w_in  = (const float*)d_in[1];   // (3072,1024)
    const float* b_in  = (const float*)d_in[2];   // (3072,)
    const float* w_out = (const float*)d_in[3];   // (1024,1024)
    const float* b_out = (const float*)d_in[4];   // (1024,)
    float* out = (float*)d_out;                   // (2,2048,1024) fp32

    char* ws = (char*)d_ws;
    ushort_t* wob = (ushort_t*)(ws);               // 2 MB: w_out bf16
    ushort_t* Wvb = (ushort_t*)(ws + (2u << 20));  // 2 MB: w_in v-rows bf16
    ushort_t* Vb  = (ushort_t*)(ws + (4u << 20));  // 8 MB: v' bf16

    prep<<<384, 256, 0, stream>>>(w_in, w_out, wob, Wvb);
    gemm_a<<<256, 256, 0, stream>>>(x, Wvb, b_in, Vb);
    gemm_b<<<256, 256, 0, stream>>>(Vb, wob, b_out, out);
}

// Round 7
// 36.329 us; speedup vs baseline: 1.3241x; 1.3241x over previous
//
#include <hip/hip_runtime.h>

typedef unsigned short ushort_t;
typedef __bf16 bf16x8 __attribute__((ext_vector_type(8)));
typedef float f32x4 __attribute__((ext_vector_type(4)));

static __device__ __forceinline__ ushort_t f2bf(float f) {
    __bf16 b = (__bf16)f;   // RNE convert
    return __builtin_bit_cast(ushort_t, b);
}

#define GLOAD_LDS16(gptr, lptr)                                                        \
    __builtin_amdgcn_global_load_lds(                                                  \
        (const __attribute__((address_space(1))) void*)(gptr),                         \
        (__attribute__((address_space(3))) void*)(lptr), 16, 0, 0)

#define CFENCE() asm volatile("" ::: "memory")

template <int N> __device__ __forceinline__ void waitcnt_vm() {
    if constexpr (N == 0)      asm volatile("s_waitcnt vmcnt(0)" ::: "memory");
    else if constexpr (N == 2) asm volatile("s_waitcnt vmcnt(2)" ::: "memory");
    else if constexpr (N == 4) asm volatile("s_waitcnt vmcnt(4)" ::: "memory");
    else if constexpr (N == 8) asm volatile("s_waitcnt vmcnt(8)" ::: "memory");
}

// ---------------------------------------------------------------------------
// Triple-buffered GEMM core: C[M][N] = A[M][K] @ B[N][K]^T (+bias), bf16 in.
// THREADS threads, waves (WGM x WGN). BK=32. Depth-2 counted-vmcnt prefetch:
// tiles t+1, t+2 stay in flight; steady-state wait is vmcnt(2L), never 0.
template <int BM, int BN, int WGM, int WGN, int THREADS, bool BF16_OUT>
__device__ __forceinline__
void gemm_core(const ushort_t* __restrict__ A, const ushort_t* __restrict__ B,
               const float* __restrict__ bias, void* __restrict__ C,
               const int K, const int N, const int rA, const int rB,
               ushort_t* ls) {
    constexpr int WM = BM / WGM, WN = BN / WGN;
    constexpr int MI = WM / 16, NJ = WN / 16;
    constexpr int LA = (BM * 32) / (8 * THREADS);   // 16B chunks per thread (A)
    constexpr int LB = (BN * 32) / (8 * THREADS);
    constexpr int L  = LA + LB;
    constexpr int HALF = (BM + BN) * 32;            // ushorts per buffer

    const int tid  = threadIdx.x;
    const int lane = tid & 63;
    const int wv   = tid >> 6;
    const int wr   = wv / WGN, wc = wv % WGN;
    const int fr   = lane & 15, fq = lane >> 4;

    f32x4 acc[MI][NJ] = {};

    auto stage = [&](int k0, int buf) {
        #pragma unroll
        for (int q = 0; q < LA; ++q) {
            int c = q * THREADS + tid;
            GLOAD_LDS16(A + (size_t)(rA + (c >> 2)) * K + k0 + (c & 3) * 8,
                        &ls[buf * HALF + c * 8]);
        }
        #pragma unroll
        for (int q = 0; q < LB; ++q) {
            int c = q * THREADS + tid;
            GLOAD_LDS16(B + (size_t)(rB + (c >> 2)) * K + k0 + (c & 3) * 8,
                        &ls[buf * HALF + BM * 32 + c * 8]);
        }
    };

    auto compute = [&](int buf) {
        bf16x8 af[MI], bfv[NJ];
        #pragma unroll
        for (int i = 0; i < MI; ++i)
            af[i] = *(const bf16x8*)&ls[buf * HALF + (wr * WM + i * 16 + fr) * 32 + fq * 8];
        #pragma unroll
        for (int j = 0; j < NJ; ++j)
            bfv[j] = *(const bf16x8*)&ls[buf * HALF + BM * 32 + (wc * WN + j * 16 + fr) * 32 + fq * 8];
        #pragma unroll
        for (int i = 0; i < MI; ++i)
            #pragma unroll
            for (int j = 0; j < NJ; ++j)
                acc[i][j] = __builtin_amdgcn_mfma_f32_16x16x32_bf16(af[i], bfv[j], acc[i][j], 0, 0, 0);
    };

    const int T = K >> 5;                        // requires T >= 3
    stage(0, 0);
    stage(32, 1);
    int cur = 0, nxt2 = 2;
    for (int t = 0; t < T - 2; ++t) {
        stage((t + 2) << 5, nxt2);               // issue tile t+2
        waitcnt_vm<2 * L>();                     // tile t landed; t+1,t+2 in flight
        __builtin_amdgcn_s_barrier(); CFENCE();
        compute(cur);
        CFENCE(); __builtin_amdgcn_s_barrier(); CFENCE();
        cur  = (cur  + 1 == 3) ? 0 : cur  + 1;
        nxt2 = (nxt2 + 1 == 3) ? 0 : nxt2 + 1;
    }
    waitcnt_vm<L>();                             // tile T-2 landed
    __builtin_amdgcn_s_barrier(); CFENCE();
    compute(cur);
    cur = (cur + 1 == 3) ? 0 : cur + 1;
    CFENCE();
    waitcnt_vm<0>();                             // tile T-1 landed
    __builtin_amdgcn_s_barrier(); CFENCE();
    compute(cur);

    const int orow0 = rA + wr * WM + fq * 4;
    const int ocol0 = rB + wc * WN + fr;
    #pragma unroll
    for (int i = 0; i < MI; ++i)
        #pragma unroll
        for (int j = 0; j < NJ; ++j) {
            const int col = ocol0 + j * 16;
            const float bv = bias ? bias[col] : 0.f;
            #pragma unroll
            for (int r = 0; r < 4; ++r) {
                const int row = orow0 + i * 16 + r;
                const float v = acc[i][j][r] + bv;
                if constexpr (BF16_OUT)
                    ((ushort_t*)C)[(size_t)row * N + col] = f2bf(v);
                else
                    ((float*)C)[(size_t)row * N + col] = v;
            }
        }
}

// ---------------------------------------------------------------------------
// L1: small prep. blocks [0,128): w_out->bf16; [128,384): Pt gather;
//     [384,640): bfused rows.
__global__ __launch_bounds__(256)
void prep(const float* __restrict__ w_in, const float* __restrict__ b_in,
          const float* __restrict__ w_out, const float* __restrict__ b_out,
          ushort_t* __restrict__ wob, ushort_t* __restrict__ Pt,
          float* __restrict__ bfused) {
    __shared__ ushort_t tile[64][65];
    const int b = blockIdx.x;
    const int t = threadIdx.x;

    if (b < 128) {
        #pragma unroll
        for (int p = 0; p < 8; ++p) {
            int i = b * 2048 + p * 256 + t;
            float4 v = ((const float4*)w_out)[i];
            ushort4 o; o.x = f2bf(v.x); o.y = f2bf(v.y); o.z = f2bf(v.z); o.w = f2bf(v.w);
            ((ushort4*)wob)[i] = o;
        }
    } else if (b < 384) {
        const int g = b - 128;
        const int gx = g & 15, gy = g >> 4;
        #pragma unroll
        for (int p = 0; p < 16; ++p) {
            int e = p * 256 + t;
            int j = e >> 6, c = e & 63;
            tile[j][c] = f2bf(w_in[(size_t)(gx * 192 + 128 + j) * 1024 + gy * 64 + c]);
        }
        __syncthreads();
        #pragma unroll
        for (int p = 0; p < 16; ++p) {
            int e = p * 256 + t;
            int c = e >> 6, j = e & 63;
            Pt[(size_t)(gy * 64 + c) * 1024 + gx * 64 + j] = tile[j][c];
        }
    } else {
        const int w = t >> 6, lane = t & 63;
        const int row = (b - 384) * 4 + w;
        float s = 0.f;
        #pragma unroll
        for (int it = 0; it < 16; ++it) {
            int j = it * 64 + lane;
            int r = (j >> 6) * 192 + 128 + (j & 63);
            s += w_out[(size_t)row * 1024 + j] * b_in[r];
        }
        #pragma unroll
        for (int off = 32; off; off >>= 1) s += __shfl_down(s, off, 64);
        if (lane == 0) bfused[row] = s + b_out[row];
    }
}

// ---------------------------------------------------------------------------
// L2: blocks [0,256): Wf = wob @ Pt^T (64x64 tiles, XCD-swizzled);
//     blocks [256,768): x fp32 -> bf16 (independent, overlaps the GEMM).
__global__ __launch_bounds__(256)
void k2(const ushort_t* __restrict__ wob, const ushort_t* __restrict__ Pt,
        ushort_t* __restrict__ Wfb,
        const float* __restrict__ x, ushort_t* __restrict__ xb) {
    __shared__ alignas(16) ushort_t ls[3 * (64 + 64) * 32];
    const int b = blockIdx.x;
    if (b < 256) {
        const int swz = (b & 7) * 32 + (b >> 3);
        const int by = swz >> 4, bx = swz & 15;
        gemm_core<64, 64, 2, 2, 256, true>(wob, Pt, nullptr, (void*)Wfb, 1024, 1024,
                                           by * 64, bx * 64, ls);
    } else {
        const int g = b - 256;
        const int t = threadIdx.x;
        #pragma unroll
        for (int p = 0; p < 8; ++p) {
            int i = g * 2048 + p * 256 + t;
            float4 v = ((const float4*)x)[i];
            ushort4 o; o.x = f2bf(v.x); o.y = f2bf(v.y); o.z = f2bf(v.z); o.w = f2bf(v.w);
            ((ushort4*)xb)[i] = o;
        }
    }
}

// ---------------------------------------------------------------------------
// L3: out = xb @ Wfb^T + bfused. 128x128 tiles, 8 waves (2x4, per-wave 64x32),
//     512 threads -> 2 waves/SIMD so ds_read and MFMA overlap across waves.
//     256 blocks (1/CU), triple-buffered counted vmcnt, XCD-swizzled.
__global__ __launch_bounds__(512)
void k3(const ushort_t* __restrict__ xb, const ushort_t* __restrict__ Wfb,
        const float* __restrict__ bfused, float* __restrict__ out) {
    __shared__ alignas(16) ushort_t ls[3 * (128 + 128) * 32];
    const int b = blockIdx.x;
    const int swz = (b & 7) * 32 + (b >> 3);
    const int by = swz >> 3, bx = swz & 7;      // 32 M-tiles x 8 N-tiles
    gemm_core<128, 128, 2, 4, 512, false>(xb, Wfb, bfused, (void*)out, 1024, 1024,
                                          by * 128, bx * 128, ls);
}

// ---------------------------------------------------------------------------
extern "C" void kernel_launch(void* const* d_in, const int* in_sizes, int n_in,
                              void* d_out, int out_size, void* d_ws, size_t ws_size,
                              hipStream_t stream) {
    const float* x     = (const float*)d_in[0];   // (2,2048,1024)
    const float* w_in  = (const float*)d_in[1];   // (3072,1024)
    const float* b_in  = (const float*)d_in[2];   // (3072,)
    const float* w_out = (const float*)d_in[3];   // (1024,1024)
    const float* b_out = (const float*)d_in[4];   // (1024,)
    float* out = (float*)d_out;                   // (2,2048,1024) fp32

    char* ws = (char*)d_ws;
    ushort_t* xb     = (ushort_t*)(ws);                      // 8 MB
    ushort_t* wob    = (ushort_t*)(ws + (8u  << 20));        // 2 MB
    ushort_t* Pt     = (ushort_t*)(ws + (10u << 20));        // 2 MB
    ushort_t* Wfb    = (ushort_t*)(ws + (12u << 20));        // 2 MB
    float*    bfused = (float*)   (ws + (14u << 20));        // 4 KB

    prep<<<640, 256, 0, stream>>>(w_in, b_in, w_out, b_out, wob, Pt, bfused);
    k2<<<768, 256, 0, stream>>>(wob, Pt, Wfb, x, xb);
    k3<<<256, 512, 0, stream>>>(xb, Wfb, bfused, out);
}

// Round 8
// 32.956 us; speedup vs baseline: 1.4596x; 1.1023x over previous
//
#include <hip/hip_runtime.h>

typedef unsigned short ushort_t;
typedef __bf16 bf16x8 __attribute__((ext_vector_type(8)));
typedef float f32x4 __attribute__((ext_vector_type(4)));

static __device__ __forceinline__ ushort_t f2bf(float f) {
    __bf16 b = (__bf16)f;   // RNE convert
    return __builtin_bit_cast(ushort_t, b);
}

#define GLOAD_LDS16(gptr, lptr)                                                        \
    __builtin_amdgcn_global_load_lds(                                                  \
        (const __attribute__((address_space(1))) void*)(gptr),                         \
        (__attribute__((address_space(3))) void*)(lptr), 16, 0, 0)

#define CFENCE() asm volatile("" ::: "memory")
#define LGKM0_SCHED() do { asm volatile("s_waitcnt lgkmcnt(0)" ::: "memory");          \
                           __builtin_amdgcn_sched_barrier(0); } while (0)

template <int N> __device__ __forceinline__ void waitcnt_vm() {
    if constexpr (N == 0)      asm volatile("s_waitcnt vmcnt(0)" ::: "memory");
    else if constexpr (N == 4) asm volatile("s_waitcnt vmcnt(4)" ::: "memory");
    else if constexpr (N == 8) asm volatile("s_waitcnt vmcnt(8)" ::: "memory");
}

// ---------------------------------------------------------------------------
// Triple-buffered, bank-conflict-free GEMM core.
// C[M][N] = A[M][K] @ B[N][K]^T (+bias), bf16 in. BK=64 (128B LDS rows).
// LDS layout: lds[row*64 + s*8 .. +8) = tile[row][ (s ^ (row&7))*8 .. +8 )
//   - staged by global_load_lds with PRE-SWIZZLED global source (linear dest)
//   - ds_read applies the same XOR -> rows 0-7 hit 8 distinct 16B slots:
//     2 lanes/bank = conflict-free (G4 attn fix, rule-21 both-sides form).
// Depth-2 counted-vmcnt prefetch: steady-state wait vmcnt(8), never 0.
template <int BM, int BN, int WGM, int WGN, int THREADS, bool BF16_OUT>
__device__ __forceinline__
void gemm_core64(const ushort_t* __restrict__ A, const ushort_t* __restrict__ B,
                 const float* __restrict__ bias, void* __restrict__ C,
                 const int K, const int N, const int rA, const int rB,
                 ushort_t* ls) {
    constexpr int WM = BM / WGM, WN = BN / WGN;
    constexpr int MI = WM / 16, NJ = WN / 16;
    constexpr int LA = (BM * 8) / THREADS;      // 16B chunks per thread (A)
    constexpr int LB = (BN * 8) / THREADS;
    constexpr int L  = LA + LB;                  // = 4 for both instantiations
    constexpr int HALF = (BM + BN) * 64;         // ushorts per buffer

    const int tid  = threadIdx.x;
    const int lane = tid & 63;
    const int wv   = tid >> 6;
    const int wr   = wv / WGN, wc = wv % WGN;
    const int fr   = lane & 15, fq = lane >> 4;

    f32x4 acc[MI][NJ] = {};

    auto stage = [&](int k0, int buf) {
        #pragma unroll
        for (int q = 0; q < LA; ++q) {
            int c = q * THREADS + tid;
            int row = c >> 3;
            int u = (c & 7) ^ (row & 7);         // pre-swizzled global 16B-unit
            GLOAD_LDS16(A + (size_t)(rA + row) * K + k0 + u * 8,
                        &ls[buf * HALF + c * 8]);
        }
        #pragma unroll
        for (int q = 0; q < LB; ++q) {
            int c = q * THREADS + tid;
            int row = c >> 3;
            int u = (c & 7) ^ (row & 7);
            GLOAD_LDS16(B + (size_t)(rB + row) * K + k0 + u * 8,
                        &ls[buf * HALF + BM * 64 + c * 8]);
        }
    };

    auto compute = [&](int buf) {
        #pragma unroll
        for (int sub = 0; sub < 2; ++sub) {
            const int u = sub * 4 + fq;
            bf16x8 af[MI], bfv[NJ];
            #pragma unroll
            for (int i = 0; i < MI; ++i) {
                const int row = wr * WM + i * 16 + fr;
                af[i] = *(const bf16x8*)&ls[buf * HALF + row * 64 + (u ^ (row & 7)) * 8];
            }
            #pragma unroll
            for (int j = 0; j < NJ; ++j) {
                const int row = wc * WN + j * 16 + fr;
                bfv[j] = *(const bf16x8*)&ls[buf * HALF + BM * 64 + row * 64 + (u ^ (row & 7)) * 8];
            }
            #pragma unroll
            for (int i = 0; i < MI; ++i)
                #pragma unroll
                for (int j = 0; j < NJ; ++j)
                    acc[i][j] = __builtin_amdgcn_mfma_f32_16x16x32_bf16(af[i], bfv[j], acc[i][j], 0, 0, 0);
        }
    };

    const int T = K >> 6;                        // BK=64; requires T >= 3
    stage(0, 0);
    stage(64, 1);
    int cur = 0, nxt2 = 2;
    for (int t = 0; t < T - 2; ++t) {
        stage((t + 2) << 6, nxt2);               // issue tile t+2
        waitcnt_vm<2 * L>();                     // tile t landed; t+1,t+2 in flight
        __builtin_amdgcn_s_barrier(); CFENCE();
        compute(cur);
        LGKM0_SCHED();                           // ds_reads complete before barrier
        __builtin_amdgcn_s_barrier(); CFENCE();
        cur  = (cur  + 1 == 3) ? 0 : cur  + 1;
        nxt2 = (nxt2 + 1 == 3) ? 0 : nxt2 + 1;
    }
    waitcnt_vm<L>();                             // tile T-2 landed
    __builtin_amdgcn_s_barrier(); CFENCE();
    compute(cur);
    cur = (cur + 1 == 3) ? 0 : cur + 1;
    LGKM0_SCHED();
    waitcnt_vm<0>();                             // tile T-1 landed
    __builtin_amdgcn_s_barrier(); CFENCE();
    compute(cur);

    const int orow0 = rA + wr * WM + fq * 4;
    const int ocol0 = rB + wc * WN + fr;
    #pragma unroll
    for (int i = 0; i < MI; ++i)
        #pragma unroll
        for (int j = 0; j < NJ; ++j) {
            const int col = ocol0 + j * 16;
            const float bv = bias ? bias[col] : 0.f;
            #pragma unroll
            for (int r = 0; r < 4; ++r) {
                const int row = orow0 + i * 16 + r;
                const float v = acc[i][j][r] + bv;
                if constexpr (BF16_OUT)
                    ((ushort_t*)C)[(size_t)row * N + col] = f2bf(v);
                else
                    ((float*)C)[(size_t)row * N + col] = v;
            }
        }
}

// ---------------------------------------------------------------------------
// L1: small prep. blocks [0,128): w_out->bf16; [128,384): Pt gather;
//     [384,640): bfused rows.
__global__ __launch_bounds__(256)
void prep(const float* __restrict__ w_in, const float* __restrict__ b_in,
          const float* __restrict__ w_out, const float* __restrict__ b_out,
          ushort_t* __restrict__ wob, ushort_t* __restrict__ Pt,
          float* __restrict__ bfused) {
    __shared__ ushort_t tile[64][65];
    const int b = blockIdx.x;
    const int t = threadIdx.x;

    if (b < 128) {
        #pragma unroll
        for (int p = 0; p < 8; ++p) {
            int i = b * 2048 + p * 256 + t;
            float4 v = ((const float4*)w_out)[i];
            ushort4 o; o.x = f2bf(v.x); o.y = f2bf(v.y); o.z = f2bf(v.z); o.w = f2bf(v.w);
            ((ushort4*)wob)[i] = o;
        }
    } else if (b < 384) {
        const int g = b - 128;
        const int gx = g & 15, gy = g >> 4;
        #pragma unroll
        for (int p = 0; p < 16; ++p) {
            int e = p * 256 + t;
            int j = e >> 6, c = e & 63;
            tile[j][c] = f2bf(w_in[(size_t)(gx * 192 + 128 + j) * 1024 + gy * 64 + c]);
        }
        __syncthreads();
        #pragma unroll
        for (int p = 0; p < 16; ++p) {
            int e = p * 256 + t;
            int c = e >> 6, j = e & 63;
            Pt[(size_t)(gy * 64 + c) * 1024 + gx * 64 + j] = tile[j][c];
        }
    } else {
        const int w = t >> 6, lane = t & 63;
        const int row = (b - 384) * 4 + w;
        float s = 0.f;
        #pragma unroll
        for (int it = 0; it < 16; ++it) {
            int j = it * 64 + lane;
            int r = (j >> 6) * 192 + 128 + (j & 63);
            s += w_out[(size_t)row * 1024 + j] * b_in[r];
        }
        #pragma unroll
        for (int off = 32; off; off >>= 1) s += __shfl_down(s, off, 64);
        if (lane == 0) bfused[row] = s + b_out[row];
    }
}

// ---------------------------------------------------------------------------
// L2: blocks [0,256): Wf = wob @ Pt^T (64x64 tiles, XCD-swizzled, BK=64 core);
//     blocks [256,768): x fp32 -> bf16 (independent, overlaps the GEMM).
__global__ __launch_bounds__(256)
void k2(const ushort_t* __restrict__ wob, const ushort_t* __restrict__ Pt,
        ushort_t* __restrict__ Wfb,
        const float* __restrict__ x, ushort_t* __restrict__ xb) {
    __shared__ alignas(16) ushort_t ls[3 * (64 + 64) * 64];
    const int b = blockIdx.x;
    if (b < 256) {
        const int swz = (b & 7) * 32 + (b >> 3);
        const int by = swz >> 4, bx = swz & 15;
        gemm_core64<64, 64, 2, 2, 256, true>(wob, Pt, nullptr, (void*)Wfb, 1024, 1024,
                                             by * 64, bx * 64, ls);
    } else {
        const int g = b - 256;
        const int t = threadIdx.x;
        #pragma unroll
        for (int p = 0; p < 8; ++p) {
            int i = g * 2048 + p * 256 + t;
            float4 v = ((const float4*)x)[i];
            ushort4 o; o.x = f2bf(v.x); o.y = f2bf(v.y); o.z = f2bf(v.z); o.w = f2bf(v.w);
            ((ushort4*)xb)[i] = o;
        }
    }
}

// ---------------------------------------------------------------------------
// L3: out = xb @ Wfb^T + bfused. 128x128 tiles, 8 waves (2x4, per-wave 64x32),
//     512 threads, 256 blocks (1/CU), BK=64 conflict-free core, XCD-swizzled.
__global__ __launch_bounds__(512)
void k3(const ushort_t* __restrict__ xb, const ushort_t* __restrict__ Wfb,
        const float* __restrict__ bfused, float* __restrict__ out) {
    __shared__ alignas(16) ushort_t ls[3 * (128 + 128) * 64];   // 96 KB
    const int b = blockIdx.x;
    const int swz = (b & 7) * 32 + (b >> 3);
    const int by = swz >> 3, bx = swz & 7;      // 32 M-tiles x 8 N-tiles
    gemm_core64<128, 128, 2, 4, 512, false>(xb, Wfb, bfused, (void*)out, 1024, 1024,
                                            by * 128, bx * 128, ls);
}

// ---------------------------------------------------------------------------
extern "C" void kernel_launch(void* const* d_in, const int* in_sizes, int n_in,
                              void* d_out, int out_size, void* d_ws, size_t ws_size,
                              hipStream_t stream) {
    const float* x     = (const float*)d_in[0];   // (2,2048,1024)
    const float* w_in  = (const float*)d_in[1];   // (3072,1024)
    const float* b_in  = (const float*)d_in[2];   // (3072,)
    const float* w_out = (const float*)d_in[3];   // (1024,1024)
    const float* b_out = (const float*)d_in[4];   // (1024,)
    float* out = (float*)d_out;                   // (2,2048,1024) fp32

    char* ws = (char*)d_ws;
    ushort_t* xb     = (ushort_t*)(ws);                      // 8 MB
    ushort_t* wob    = (ushort_t*)(ws + (8u  << 20));        // 2 MB
    ushort_t* Pt     = (ushort_t*)(ws + (10u << 20));        // 2 MB
    ushort_t* Wfb    = (ushort_t*)(ws + (12u << 20));        // 2 MB
    float*    bfused = (float*)   (ws + (14u << 20));        // 4 KB

    prep<<<640, 256, 0, stream>>>(w_in, b_in, w_out, b_out, wob, Pt, bfused);
    k2<<<768, 256, 0, stream>>>(wob, Pt, Wfb, x, xb);
    k3<<<256, 512, 0, stream>>>(xb, Wfb, bfused, out);
}